// Round 2
// baseline (214.440 us; speedup 1.0000x reference)
//
#include <hip/hip_runtime.h>

#define SEQ 2048

typedef short short8 __attribute__((ext_vector_type(8)));   // 8 bf16 (4 VGPRs)
typedef float floatx4 __attribute__((ext_vector_type(4)));  // 4 fp32 acc
typedef unsigned short ushort4v __attribute__((ext_vector_type(4)));
typedef unsigned int uint2v __attribute__((ext_vector_type(2)));
typedef __fp16 f16x4 __attribute__((ext_vector_type(4)));   // matches V4h builtin operand

static __device__ __forceinline__ unsigned short f2bf(float f) {
    unsigned int u = __builtin_bit_cast(unsigned int, f);
    u = (u + 0x7fffu + ((u >> 16) & 1u)) >> 16;   // RNE
    return (unsigned short)u;
}

// pack two fp32 -> two bf16 (RNE); HW instr if available (round-6 proven)
#if __has_builtin(__builtin_amdgcn_cvt_pk_bf16_f32)
typedef __bf16 bf16x2 __attribute__((ext_vector_type(2)));
static __device__ __forceinline__ unsigned int pk_bf16(float a, float b) {
    bf16x2 v = __builtin_amdgcn_cvt_pk_bf16_f32(a, b);
    return __builtin_bit_cast(unsigned int, v);
}
#else
static __device__ __forceinline__ unsigned int pk_bf16(float a, float b) {
    return (unsigned int)f2bf(a) | ((unsigned int)f2bf(b) << 16);
}
#endif

// pack two fp32 -> two fp16 (RTZ); return raw u32
static __device__ __forceinline__ unsigned int pk_f16(float a, float b) {
    auto v = __builtin_amdgcn_cvt_pkrtz(a, b);    // __fp16 x2
    return __builtin_bit_cast(unsigned int, v);
}

// async global->LDS, 16 B/lane; LDS dest = wave-uniform base + lane*16
#define GLD16(gp, lp)                                                        \
    __builtin_amdgcn_global_load_lds(                                        \
        (const __attribute__((address_space(1))) unsigned int*)(gp),         \
        (__attribute__((address_space(3))) unsigned int*)(lp), 16, 0, 0)

// ---------------- fused fp32 -> bf16 convert (x_t scaled, x_s plain) ----------------
__global__ void cvt2_kernel(const float4* __restrict__ a, const float4* __restrict__ b,
                            ushort4* __restrict__ oa, ushort4* __restrict__ ob, float sa) {
    int i = blockIdx.x * blockDim.x + threadIdx.x;
    if (i < 1048576) {
        float4 v = a[i];
        ushort4 o;
        o.x = f2bf(v.x * sa); o.y = f2bf(v.y * sa);
        o.z = f2bf(v.z * sa); o.w = f2bf(v.w * sa);
        oa[i] = o;
    } else {
        int j = i - 1048576;
        float4 v = b[j];
        ushort4 o;
        o.x = f2bf(v.x); o.y = f2bf(v.y);
        o.z = f2bf(v.z); o.w = f2bf(v.w);
        ob[j] = o;
    }
}

// ---------------- merged weight transposes: W [K][N] fp32 -> Wt [N][K] bf16 --------
__global__ void transpose_all(const float* __restrict__ Wq, const float* __restrict__ Wkv,
                              const float* __restrict__ Wf,
                              unsigned short* __restrict__ oq, unsigned short* __restrict__ okv,
                              unsigned short* __restrict__ of_) {
    __shared__ float tile[32][33];
    int bx = blockIdx.x;
    const float* in; unsigned short* out; int N, t;
    if (bx < 1024)      { in = Wq;  out = oq;  N = 1024; t = bx; }
    else if (bx < 3072) { in = Wkv; out = okv; N = 2048; t = bx - 1024; }
    else                { in = Wf;  out = of_; N = 1024; t = bx - 3072; }
    int nb = N >> 5;
    int n0 = (t % nb) * 32, k0 = (t / nb) * 32;   // K = 1024 always
    int tx = threadIdx.x, ty = threadIdx.y;
#pragma unroll
    for (int i = 0; i < 4; i++)
        tile[ty + i * 8][tx] = in[(size_t)(k0 + ty + i * 8) * N + n0 + tx];
    __syncthreads();
#pragma unroll
    for (int i = 0; i < 4; i++)
        out[(size_t)(n0 + ty + i * 8) * 1024 + k0 + tx] = f2bf(tile[tx][ty + i * 8]);
}

// ---------------- fused q+kv projection GEMM ----------------
// Epilogue: K written PRE-SWIZZLED bf16 (d ^ ((n&7)<<3)) and V^T written
// PRE-SWIZZLED fp16 so attn can global_load_lds with linear dest (m173 pattern).
__global__ __launch_bounds__(256, 3)
void gemm_qkv(const unsigned short* __restrict__ xt,
              const unsigned short* __restrict__ xs,
              const unsigned short* __restrict__ wq,
              const unsigned short* __restrict__ wkv,
              unsigned short* __restrict__ q_ws,
              unsigned short* __restrict__ k_ws,
              unsigned short* __restrict__ vt_ws) {
    __shared__ unsigned short sA[128][64];   // unpadded: required by global_load_lds
    __shared__ unsigned short sB[128][64];
    int tid = threadIdx.x, wave = tid >> 6, lane = tid & 63;
    int l15 = lane & 15, quad = lane >> 4;
    int cx = blockIdx.x;
    bool isq = cx < 8;
    const unsigned short* A  = isq ? xt : xs;
    const unsigned short* Bt = isq ? wq : wkv;
    int C0 = (isq ? cx : cx - 8) * 128;
    int R0 = blockIdx.y * 128;
    int wr = (wave >> 1) * 64, wc = (wave & 1) * 64;
    int srow = lane >> 3, scol = (lane & 7) * 8;   // staging: 8 rows / 1KB call

    floatx4 acc[4][4];
#pragma unroll
    for (int i = 0; i < 4; i++)
#pragma unroll
        for (int j = 0; j < 4; j++) acc[i][j] = (floatx4){0.f, 0.f, 0.f, 0.f};

    for (int kt = 0; kt < 16; kt++) {
        __syncthreads();                       // prev tile reads done
#pragma unroll
        for (int c = 0; c < 4; c++) {
            int rb = wave * 32 + c * 8;        // wave-uniform LDS dest row
            GLD16(&A [(size_t)(R0 + rb + srow) * 1024 + kt * 64 + scol], &sA[rb][0]);
            GLD16(&Bt[(size_t)(C0 + rb + srow) * 1024 + kt * 64 + scol], &sB[rb][0]);
        }
        __syncthreads();                       // vmcnt(0) drain + barrier
#pragma unroll
        for (int ks = 0; ks < 2; ks++) {
            short8 af[4], bf[4];
#pragma unroll
            for (int mt = 0; mt < 4; mt++)
                af[mt] = *(const short8*)&sA[wr + mt * 16 + l15][ks * 32 + quad * 8];
#pragma unroll
            for (int nt = 0; nt < 4; nt++)
                bf[nt] = *(const short8*)&sB[wc + nt * 16 + l15][ks * 32 + quad * 8];
#pragma unroll
            for (int mt = 0; mt < 4; mt++)
#pragma unroll
                for (int nt = 0; nt < 4; nt++)
                    acc[mt][nt] = __builtin_amdgcn_mfma_f32_16x16x32_bf16(af[mt], bf[nt], acc[mt][nt], 0, 0, 0);
        }
    }

    int b = R0 >> 11, nb0 = (R0 & 2047) + wr;  // 128-row tile stays within one batch
#pragma unroll
    for (int mt = 0; mt < 4; mt++) {
#pragma unroll
        for (int nt = 0; nt < 4; nt++) {
            int col = C0 + wc + nt * 16 + l15;     // C/D: col=lane&15
            if (isq) {
                int h = col >> 6, d = col & 63;
#pragma unroll
                for (int r = 0; r < 4; r++) {      // C/D: row=quad*4+reg
                    int n = nb0 + mt * 16 + quad * 4 + r;
                    q_ws[((size_t)((b * 16 + h) * 2048 + n)) * 64 + d] = f2bf(acc[mt][nt][r]);
                }
            } else if (col < 1024) {               // k half: bf16, pre-swizzled
                int h = col >> 6, d = col & 63;
#pragma unroll
                for (int r = 0; r < 4; r++) {
                    int n = nb0 + mt * 16 + quad * 4 + r;
                    k_ws[((size_t)((b * 16 + h) * 2048 + n)) * 64 + (d ^ ((n & 7) << 3))] = f2bf(acc[mt][nt][r]);
                }
            } else {                               // v half -> fp16 vt[bh][d][n'], pre-swizzled
                int cc = col - 1024, h = cc >> 6, d = cc & 63;
                int n0 = nb0 + mt * 16 + quad * 4;
                int coln = (n0 & ~63) | ((n0 & 63) ^ ((d & 7) << 3));  // swz keeps 4-groups intact
                uint2v pk;
                pk.x = pk_f16(acc[mt][nt][0], acc[mt][nt][1]);
                pk.y = pk_f16(acc[mt][nt][2], acc[mt][nt][3]);
                *(uint2v*)&vt_ws[((size_t)((b * 16 + h) * 64 + d)) * 2048 + coln] = pk;
            }
        }
    }
}

// ---------------- fuse GEMM (round-5 proven version) ----------------
__global__ __launch_bounds__(256, 3)
void gemm_fuse(const unsigned short* __restrict__ A,
               const unsigned short* __restrict__ Bt,
               float* __restrict__ out, const float* __restrict__ bias) {
    __shared__ unsigned short sA[128][64];
    __shared__ unsigned short sB[64][64];
    int tid = threadIdx.x, wave = tid >> 6, lane = tid & 63;
    int l15 = lane & 15, quad = lane >> 4;
    int R0 = blockIdx.y * 128, C0 = blockIdx.x * 64;
    int wr = (wave >> 1) * 64, wc = (wave & 1) * 32;
    int srow = lane >> 3, scol = (lane & 7) * 8;

    floatx4 acc[4][2];
#pragma unroll
    for (int i = 0; i < 4; i++)
#pragma unroll
        for (int j = 0; j < 2; j++) acc[i][j] = (floatx4){0.f, 0.f, 0.f, 0.f};

    for (int kt = 0; kt < 16; kt++) {
        __syncthreads();
#pragma unroll
        for (int c = 0; c < 4; c++) {
            int rb = wave * 32 + c * 8;
            GLD16(&A[(size_t)(R0 + rb + srow) * 1024 + kt * 64 + scol], &sA[rb][0]);
        }
#pragma unroll
        for (int c = 0; c < 2; c++) {
            int rb = wave * 16 + c * 8;
            GLD16(&Bt[(size_t)(C0 + rb + srow) * 1024 + kt * 64 + scol], &sB[rb][0]);
        }
        __syncthreads();
#pragma unroll
        for (int ks = 0; ks < 2; ks++) {
            short8 af[4], bf[2];
#pragma unroll
            for (int mt = 0; mt < 4; mt++)
                af[mt] = *(const short8*)&sA[wr + mt * 16 + l15][ks * 32 + quad * 8];
#pragma unroll
            for (int nt = 0; nt < 2; nt++)
                bf[nt] = *(const short8*)&sB[wc + nt * 16 + l15][ks * 32 + quad * 8];
#pragma unroll
            for (int mt = 0; mt < 4; mt++)
#pragma unroll
                for (int nt = 0; nt < 2; nt++)
                    acc[mt][nt] = __builtin_amdgcn_mfma_f32_16x16x32_bf16(af[mt], bf[nt], acc[mt][nt], 0, 0, 0);
        }
    }

#pragma unroll
    for (int mt = 0; mt < 4; mt++) {
#pragma unroll
        for (int r = 0; r < 4; r++) {
            int row = R0 + wr + mt * 16 + quad * 4 + r;
#pragma unroll
            for (int nt = 0; nt < 2; nt++) {
                int col = C0 + wc + nt * 16 + l15;
                out[(size_t)row * 1024 + col] = acc[mt][nt][r] + bias[col];
            }
        }
    }
}

// ---------------- flash attention: key-split waves, P fully in registers ----------------
// Wave w owns keys [w*16, w*16+16) of each 64-key tile. S^T = K*Q^T (16x16x32 bf16)
// leaves P[key=quad*4+r][q=l15] in-lane, which IS the B-fragment of
// v_mfma_f32_16x16x16_f16 (k=quad*4+j, col=l15): no P LDS round-trip, no lgkmcnt.
// Q (64q x 64d) lives in registers. K/V staged by global_load_lds from
// PRE-SWIZZLED global layouts (producer = gemm_qkv). Cross-wave O reduction via
// LDS (reusing K/V buffers) at the end, static register indices only.
__global__ __launch_bounds__(256, 2)
void attn_kernel(const unsigned short* __restrict__ Q,   // [32][2048][64] bf16
                 const unsigned short* __restrict__ K,   // [32][2048][64] bf16, pre-swizzled
                 const unsigned short* __restrict__ Vt,  // [32][64][2048] fp16, pre-swizzled
                 unsigned short* __restrict__ Aout) {    // [4096][1024] bf16
    __shared__ __align__(16) unsigned short smem[16384];  // sK[2][64*64] | sV[2][64*64]; reused as red
    __shared__ float lred[4][4][16];

    int tid = threadIdx.x, wave = tid >> 6, lane = tid & 63;
    int l15 = lane & 15, quad = lane >> 4;
    int bh = blockIdx.y, b = bh >> 4, h = bh & 15;
    int qr0 = blockIdx.x * 64;

    const unsigned short* Qp = Q + (size_t)bh * SEQ * 64;
    const unsigned short* Kp = K + (size_t)bh * SEQ * 64;
    const unsigned short* Vp = Vt + (size_t)bh * 64 * SEQ;

    int srow = lane >> 3, scol = (lane & 7) * 8;   // 8 rows / 1KB per DMA call
    int wk0 = wave * 16;                           // this wave's key rows in tile

    // stage tile 0 (linear copy of pre-swizzled global; wave stages its own 16 rows)
#pragma unroll
    for (int j = 0; j < 2; j++) {
        int rb = wk0 + j * 8;
        GLD16(&Kp[(size_t)(rb + srow) * 64 + scol], &smem[rb * 64]);
        GLD16(&Vp[(size_t)(rb + srow) * 2048 + scol], &smem[8192 + rb * 64]);
    }

    // Q fragments: B-operand col=q=l15, k=ks*32+quad*8 -> direct global loads, held in regs
    short8 qf[4][2];
#pragma unroll
    for (int nt = 0; nt < 4; nt++)
#pragma unroll
        for (int ks = 0; ks < 2; ks++)
            qf[nt][ks] = *(const short8*)&Qp[(size_t)(qr0 + nt * 16 + l15) * 64 + ks * 32 + quad * 8];

    floatx4 of[4][4];   // O^T partial: [dt][nt], row=d=dt*16+quad*4+r, col=q=nt*16+l15
#pragma unroll
    for (int i = 0; i < 4; i++)
#pragma unroll
        for (int j = 0; j < 4; j++) of[i][j] = (floatx4){0.f, 0.f, 0.f, 0.f};
    float lsum[4] = {0.f, 0.f, 0.f, 0.f};

    __syncthreads();

    int krow = wk0 + l15;
    int ksw = (l15 & 7) << 3;
    int kaddr0 = krow * 64 + ((quad * 8) ^ ksw);
    int kaddr1 = krow * 64 + ((32 + quad * 8) ^ ksw);
    int vcol = (wk0 + quad * 4) ^ ksw;             // vrow&7 == l15&7 for all dt

#pragma unroll 2
    for (int kt = 0; kt < 32; kt++) {
        int p = kt & 1, pb = p * 4096;
        if (kt < 31) {                             // DMA-prefetch next tile into other buffer
            int k0n = (kt + 1) * 64;
#pragma unroll
            for (int j = 0; j < 2; j++) {
                int rb = wk0 + j * 8;
                GLD16(&Kp[(size_t)(k0n + rb + srow) * 64 + scol], &smem[(pb ^ 4096) + rb * 64]);
                GLD16(&Vp[(size_t)(rb + srow) * 2048 + k0n + scol], &smem[8192 + (pb ^ 4096) + rb * 64]);
            }
        }

        // S^T = K * Q^T over this wave's 16 keys; P stays in registers
        short8 kf0 = *(const short8*)&smem[pb + kaddr0];
        short8 kf1 = *(const short8*)&smem[pb + kaddr1];
        f16x4 pf[4];
#pragma unroll
        for (int nt = 0; nt < 4; nt++) {
            floatx4 zero = (floatx4){0.f, 0.f, 0.f, 0.f};
            floatx4 s = __builtin_amdgcn_mfma_f32_16x16x32_bf16(kf0, qf[nt][0], zero, 0, 0, 0);
            s = __builtin_amdgcn_mfma_f32_16x16x32_bf16(kf1, qf[nt][1], s, 0, 0, 0);
            float p0 = __builtin_amdgcn_exp2f(s[0]);
            float p1 = __builtin_amdgcn_exp2f(s[1]);
            float p2 = __builtin_amdgcn_exp2f(s[2]);
            float p3 = __builtin_amdgcn_exp2f(s[3]);
            lsum[nt] += (p0 + p1) + (p2 + p3);
            uint2v u;
            u.x = pk_f16(p0, p1);
            u.y = pk_f16(p2, p3);
            pf[nt] = __builtin_bit_cast(f16x4, u);
        }

        // O^T += V^T * P^T  (16x16x16 f16: A=V^T[d][k=quad*4+j], B=P in-lane)
#pragma unroll
        for (int dt = 0; dt < 4; dt++) {
            int vrow = dt * 16 + l15;
            ushort4v vv = *(const ushort4v*)&smem[8192 + pb + vrow * 64 + vcol];
            f16x4 vf = __builtin_bit_cast(f16x4, vv);
#pragma unroll
            for (int nt = 0; nt < 4; nt++)
                of[dt][nt] = __builtin_amdgcn_mfma_f32_16x16x16f16(vf, pf[nt], of[dt][nt], 0, 0, 0);
        }
        __syncthreads();                           // single barrier per key-tile
    }

    // ---- epilogue: cross-quad l reduce, then cross-wave O/l reduction via LDS ----
#pragma unroll
    for (int nt = 0; nt < 4; nt++) {
        float l = lsum[nt];
        l += __shfl_xor(l, 16, 64);
        l += __shfl_xor(l, 32, 64);
        lsum[nt] = l;
    }
    if (quad == 0) {
#pragma unroll
        for (int nt = 0; nt < 4; nt++) lred[wave][nt][l15] = lsum[nt];
    }

    float* red = (float*)smem;   // 8192 floats; slot(c,w) = ((c*4+w)*1024), layout [nt][lane][4]

#define RED_WRITE(C, DTC)                                                          \
    _Pragma("unroll")                                                              \
    for (int nt = 0; nt < 4; nt++)                                                 \
        *(floatx4*)&red[((C) * 4 + wave) * 1024 + nt * 256 + lane * 4] = of[DTC][nt];

#define RED_STORE(DT, C, W0, W1, W2)                                               \
    {                                                                              \
        size_t obase = (size_t)(b * SEQ + qr0) * 1024 + h * 64 + (DT) * 16 + quad * 4; \
        _Pragma("unroll")                                                          \
        for (int nt = 0; nt < 4; nt++) {                                           \
            floatx4 a0 = *(const floatx4*)&red[((C) * 4 + (W0)) * 1024 + nt * 256 + lane * 4]; \
            floatx4 a1 = *(const floatx4*)&red[((C) * 4 + (W1)) * 1024 + nt * 256 + lane * 4]; \
            floatx4 a2 = *(const floatx4*)&red[((C) * 4 + (W2)) * 1024 + nt * 256 + lane * 4]; \
            floatx4 s = of[DT][nt] + a0 + a1 + a2;                                 \
            float lt = lred[0][nt][l15] + lred[1][nt][l15] + lred[2][nt][l15] + lred[3][nt][l15]; \
            float inv = 1.f / lt;                                                  \
            uint2v o;                                                              \
            o.x = pk_bf16(s[0] * inv, s[1] * inv);                                 \
            o.y = pk_bf16(s[2] * inv, s[3] * inv);                                 \
            *(uint2v*)&Aout[obase + (size_t)(nt * 16 + l15) * 1024] = o;           \
        }                                                                          \
    }

    // round 1: everyone ships of[0] -> slot(0,w), of[1] -> slot(1,w)
    RED_WRITE(0, 0)
    RED_WRITE(1, 1)
    __syncthreads();
    if (wave == 0)      RED_STORE(0, 0, 1, 2, 3)
    else if (wave == 1) RED_STORE(1, 1, 0, 2, 3)
    __syncthreads();
    // round 2: everyone ships of[2] -> slot(0,w), of[3] -> slot(1,w)
    RED_WRITE(0, 2)
    RED_WRITE(1, 3)
    __syncthreads();
    if (wave == 2)      RED_STORE(2, 0, 0, 1, 3)
    else if (wave == 3) RED_STORE(3, 1, 0, 1, 2)
#undef RED_WRITE
#undef RED_STORE
}

extern "C" void kernel_launch(void* const* d_in, const int* in_sizes, int n_in,
                              void* d_out, int out_size, void* d_ws, size_t ws_size,
                              hipStream_t stream) {
    const float* x_t  = (const float*)d_in[0];
    const float* x_s  = (const float*)d_in[1];
    const float* W_q  = (const float*)d_in[2];
    const float* W_kv = (const float*)d_in[3];
    const float* W_f  = (const float*)d_in[4];
    const float* b_f  = (const float*)d_in[5];
    float* out = (float*)d_out;

    char* ws = (char*)d_ws;
    const size_t MB = 1u << 20;
    unsigned short* xt_bf = (unsigned short*)(ws);            // 8 MB
    unsigned short* xs_bf = (unsigned short*)(ws + 8 * MB);   // 8 MB
    unsigned short* wq_t  = (unsigned short*)(ws + 16 * MB);  // 2 MB
    unsigned short* wkv_t = (unsigned short*)(ws + 18 * MB);  // 4 MB
    unsigned short* wf_t  = (unsigned short*)(ws + 22 * MB);  // 2 MB
    unsigned short* q_ws  = (unsigned short*)(ws + 24 * MB);  // 8 MB
    unsigned short* k_ws  = (unsigned short*)(ws + 32 * MB);  // 8 MB (pre-swizzled)
    unsigned short* vt_ws = (unsigned short*)(ws + 40 * MB);  // 8 MB (fp16, pre-swizzled)
    unsigned short* a_ws  = (unsigned short*)(ws + 48 * MB);  // 8 MB (total 56 MB)

    // SCALE * log2(e) folded into x_t so attention logits are in log2 domain
    cvt2_kernel<<<8192, 256, 0, stream>>>((const float4*)x_t, (const float4*)x_s,
                                          (ushort4*)xt_bf, (ushort4*)xs_bf,
                                          0.125f * 1.44269504088896340736f);
    transpose_all<<<4096, dim3(32, 8), 0, stream>>>(W_q, W_kv, W_f, wq_t, wkv_t, wf_t);

    gemm_qkv<<<dim3(24, 32), 256, 0, stream>>>(xt_bf, xs_bf, wq_t, wkv_t, q_ws, k_ws, vt_ws);
    attn_kernel<<<dim3(32, 32), 256, 0, stream>>>(q_ws, k_ws, vt_ws, a_ws);
    gemm_fuse<<<dim3(16, 32), 256, 0, stream>>>(a_ws, wf_t, out, b_f);
}

// Round 3
// 213.935 us; speedup vs baseline: 1.0024x; 1.0024x over previous
//
#include <hip/hip_runtime.h>

#define SEQ 2048

typedef short short8 __attribute__((ext_vector_type(8)));   // 8 bf16 (4 VGPRs)
typedef float floatx4 __attribute__((ext_vector_type(4)));  // 4 fp32 acc
typedef unsigned short ushort4v __attribute__((ext_vector_type(4)));
typedef unsigned int uint2v __attribute__((ext_vector_type(2)));
typedef __fp16 f16x4 __attribute__((ext_vector_type(4)));   // matches V4h builtin operand

static __device__ __forceinline__ unsigned short f2bf(float f) {
    unsigned int u = __builtin_bit_cast(unsigned int, f);
    u = (u + 0x7fffu + ((u >> 16) & 1u)) >> 16;   // RNE
    return (unsigned short)u;
}

// pack two fp32 -> two bf16 (RNE); HW instr if available (round-6 proven)
#if __has_builtin(__builtin_amdgcn_cvt_pk_bf16_f32)
typedef __bf16 bf16x2 __attribute__((ext_vector_type(2)));
static __device__ __forceinline__ unsigned int pk_bf16(float a, float b) {
    bf16x2 v = __builtin_amdgcn_cvt_pk_bf16_f32(a, b);
    return __builtin_bit_cast(unsigned int, v);
}
#else
static __device__ __forceinline__ unsigned int pk_bf16(float a, float b) {
    return (unsigned int)f2bf(a) | ((unsigned int)f2bf(b) << 16);
}
#endif

// pack two fp32 -> two fp16 (RTZ); return raw u32
static __device__ __forceinline__ unsigned int pk_f16(float a, float b) {
    auto v = __builtin_amdgcn_cvt_pkrtz(a, b);    // __fp16 x2
    return __builtin_bit_cast(unsigned int, v);
}

// async global->LDS, 16 B/lane; LDS dest = wave-uniform base + lane*16
#define GLD16(gp, lp)                                                        \
    __builtin_amdgcn_global_load_lds(                                        \
        (const __attribute__((address_space(1))) unsigned int*)(gp),         \
        (__attribute__((address_space(3))) unsigned int*)(lp), 16, 0, 0)

// ---------------- fused fp32 -> bf16 convert (x_t scaled, x_s plain) ----------------
__global__ void cvt2_kernel(const float4* __restrict__ a, const float4* __restrict__ b,
                            ushort4* __restrict__ oa, ushort4* __restrict__ ob, float sa) {
    int i = blockIdx.x * blockDim.x + threadIdx.x;
    if (i < 1048576) {
        float4 v = a[i];
        ushort4 o;
        o.x = f2bf(v.x * sa); o.y = f2bf(v.y * sa);
        o.z = f2bf(v.z * sa); o.w = f2bf(v.w * sa);
        oa[i] = o;
    } else {
        int j = i - 1048576;
        float4 v = b[j];
        ushort4 o;
        o.x = f2bf(v.x); o.y = f2bf(v.y);
        o.z = f2bf(v.z); o.w = f2bf(v.w);
        ob[j] = o;
    }
}

// ---------------- merged weight transposes: W [K][N] fp32 -> Wt [N][K] bf16 --------
__global__ void transpose_all(const float* __restrict__ Wq, const float* __restrict__ Wkv,
                              const float* __restrict__ Wf,
                              unsigned short* __restrict__ oq, unsigned short* __restrict__ okv,
                              unsigned short* __restrict__ of_) {
    __shared__ float tile[32][33];
    int bx = blockIdx.x;
    const float* in; unsigned short* out; int N, t;
    if (bx < 1024)      { in = Wq;  out = oq;  N = 1024; t = bx; }
    else if (bx < 3072) { in = Wkv; out = okv; N = 2048; t = bx - 1024; }
    else                { in = Wf;  out = of_; N = 1024; t = bx - 3072; }
    int nb = N >> 5;
    int n0 = (t % nb) * 32, k0 = (t / nb) * 32;   // K = 1024 always
    int tx = threadIdx.x, ty = threadIdx.y;
#pragma unroll
    for (int i = 0; i < 4; i++)
        tile[ty + i * 8][tx] = in[(size_t)(k0 + ty + i * 8) * N + n0 + tx];
    __syncthreads();
#pragma unroll
    for (int i = 0; i < 4; i++)
        out[(size_t)(n0 + ty + i * 8) * 1024 + k0 + tx] = f2bf(tile[tx][ty + i * 8]);
}

// ---------------- fused q+kv projection GEMM ----------------
// Epilogue: K written PRE-SWIZZLED bf16 (d ^ ((n&7)<<3)) and V^T written
// PRE-SWIZZLED fp16 so attn can global_load_lds with linear dest (m173 pattern).
__global__ __launch_bounds__(256, 3)
void gemm_qkv(const unsigned short* __restrict__ xt,
              const unsigned short* __restrict__ xs,
              const unsigned short* __restrict__ wq,
              const unsigned short* __restrict__ wkv,
              unsigned short* __restrict__ q_ws,
              unsigned short* __restrict__ k_ws,
              unsigned short* __restrict__ vt_ws) {
    __shared__ unsigned short sA[128][64];   // unpadded: required by global_load_lds
    __shared__ unsigned short sB[128][64];
    int tid = threadIdx.x, wave = tid >> 6, lane = tid & 63;
    int l15 = lane & 15, quad = lane >> 4;
    int cx = blockIdx.x;
    bool isq = cx < 8;
    const unsigned short* A  = isq ? xt : xs;
    const unsigned short* Bt = isq ? wq : wkv;
    int C0 = (isq ? cx : cx - 8) * 128;
    int R0 = blockIdx.y * 128;
    int wr = (wave >> 1) * 64, wc = (wave & 1) * 64;
    int srow = lane >> 3, scol = (lane & 7) * 8;   // staging: 8 rows / 1KB call

    floatx4 acc[4][4];
#pragma unroll
    for (int i = 0; i < 4; i++)
#pragma unroll
        for (int j = 0; j < 4; j++) acc[i][j] = (floatx4){0.f, 0.f, 0.f, 0.f};

    for (int kt = 0; kt < 16; kt++) {
        __syncthreads();                       // prev tile reads done
#pragma unroll
        for (int c = 0; c < 4; c++) {
            int rb = wave * 32 + c * 8;        // wave-uniform LDS dest row
            GLD16(&A [(size_t)(R0 + rb + srow) * 1024 + kt * 64 + scol], &sA[rb][0]);
            GLD16(&Bt[(size_t)(C0 + rb + srow) * 1024 + kt * 64 + scol], &sB[rb][0]);
        }
        __syncthreads();                       // vmcnt(0) drain + barrier
#pragma unroll
        for (int ks = 0; ks < 2; ks++) {
            short8 af[4], bf[4];
#pragma unroll
            for (int mt = 0; mt < 4; mt++)
                af[mt] = *(const short8*)&sA[wr + mt * 16 + l15][ks * 32 + quad * 8];
#pragma unroll
            for (int nt = 0; nt < 4; nt++)
                bf[nt] = *(const short8*)&sB[wc + nt * 16 + l15][ks * 32 + quad * 8];
#pragma unroll
            for (int mt = 0; mt < 4; mt++)
#pragma unroll
                for (int nt = 0; nt < 4; nt++)
                    acc[mt][nt] = __builtin_amdgcn_mfma_f32_16x16x32_bf16(af[mt], bf[nt], acc[mt][nt], 0, 0, 0);
        }
    }

    int b = R0 >> 11, nb0 = (R0 & 2047) + wr;  // 128-row tile stays within one batch
#pragma unroll
    for (int mt = 0; mt < 4; mt++) {
#pragma unroll
        for (int nt = 0; nt < 4; nt++) {
            int col = C0 + wc + nt * 16 + l15;     // C/D: col=lane&15
            if (isq) {
                int h = col >> 6, d = col & 63;
#pragma unroll
                for (int r = 0; r < 4; r++) {      // C/D: row=quad*4+reg
                    int n = nb0 + mt * 16 + quad * 4 + r;
                    q_ws[((size_t)((b * 16 + h) * 2048 + n)) * 64 + d] = f2bf(acc[mt][nt][r]);
                }
            } else if (col < 1024) {               // k half: bf16, pre-swizzled
                int h = col >> 6, d = col & 63;
#pragma unroll
                for (int r = 0; r < 4; r++) {
                    int n = nb0 + mt * 16 + quad * 4 + r;
                    k_ws[((size_t)((b * 16 + h) * 2048 + n)) * 64 + (d ^ ((n & 7) << 3))] = f2bf(acc[mt][nt][r]);
                }
            } else {                               // v half -> fp16 vt[bh][d][n'], pre-swizzled
                int cc = col - 1024, h = cc >> 6, d = cc & 63;
                int n0 = nb0 + mt * 16 + quad * 4;
                int coln = (n0 & ~63) | ((n0 & 63) ^ ((d & 7) << 3));  // swz keeps 4-groups intact
                uint2v pk;
                pk.x = pk_f16(acc[mt][nt][0], acc[mt][nt][1]);
                pk.y = pk_f16(acc[mt][nt][2], acc[mt][nt][3]);
                *(uint2v*)&vt_ws[((size_t)((b * 16 + h) * 64 + d)) * 2048 + coln] = pk;
            }
        }
    }
}

// ---------------- fuse GEMM (round-5 proven version) ----------------
__global__ __launch_bounds__(256, 3)
void gemm_fuse(const unsigned short* __restrict__ A,
               const unsigned short* __restrict__ Bt,
               float* __restrict__ out, const float* __restrict__ bias) {
    __shared__ unsigned short sA[128][64];
    __shared__ unsigned short sB[64][64];
    int tid = threadIdx.x, wave = tid >> 6, lane = tid & 63;
    int l15 = lane & 15, quad = lane >> 4;
    int R0 = blockIdx.y * 128, C0 = blockIdx.x * 64;
    int wr = (wave >> 1) * 64, wc = (wave & 1) * 32;
    int srow = lane >> 3, scol = (lane & 7) * 8;

    floatx4 acc[4][2];
#pragma unroll
    for (int i = 0; i < 4; i++)
#pragma unroll
        for (int j = 0; j < 2; j++) acc[i][j] = (floatx4){0.f, 0.f, 0.f, 0.f};

    for (int kt = 0; kt < 16; kt++) {
        __syncthreads();
#pragma unroll
        for (int c = 0; c < 4; c++) {
            int rb = wave * 32 + c * 8;
            GLD16(&A[(size_t)(R0 + rb + srow) * 1024 + kt * 64 + scol], &sA[rb][0]);
        }
#pragma unroll
        for (int c = 0; c < 2; c++) {
            int rb = wave * 16 + c * 8;
            GLD16(&Bt[(size_t)(C0 + rb + srow) * 1024 + kt * 64 + scol], &sB[rb][0]);
        }
        __syncthreads();
#pragma unroll
        for (int ks = 0; ks < 2; ks++) {
            short8 af[4], bf[2];
#pragma unroll
            for (int mt = 0; mt < 4; mt++)
                af[mt] = *(const short8*)&sA[wr + mt * 16 + l15][ks * 32 + quad * 8];
#pragma unroll
            for (int nt = 0; nt < 2; nt++)
                bf[nt] = *(const short8*)&sB[wc + nt * 16 + l15][ks * 32 + quad * 8];
#pragma unroll
            for (int mt = 0; mt < 4; mt++)
#pragma unroll
                for (int nt = 0; nt < 2; nt++)
                    acc[mt][nt] = __builtin_amdgcn_mfma_f32_16x16x32_bf16(af[mt], bf[nt], acc[mt][nt], 0, 0, 0);
        }
    }

#pragma unroll
    for (int mt = 0; mt < 4; mt++) {
#pragma unroll
        for (int r = 0; r < 4; r++) {
            int row = R0 + wr + mt * 16 + quad * 4 + r;
#pragma unroll
            for (int nt = 0; nt < 2; nt++) {
                int col = C0 + wc + nt * 16 + l15;
                out[(size_t)row * 1024 + col] = acc[mt][nt][r] + bias[col];
            }
        }
    }
}

// ---------------- flash attention: key-split waves, counted-vmcnt pipeline ----------------
// Round-3 changes vs round-2 (compute math IDENTICAL):
//  (a) T4: __syncthreads-per-kt (implicit vmcnt(0) drain of just-issued DMAs) replaced
//      by {compute; s_barrier; stage(kt+2)->b_p; s_waitcnt vmcnt(4); s_barrier}:
//      prefetch DMAs get a full iteration in flight, never drained in the main loop.
//  (b) T1: bijective XCD swizzle (1024 = 8*128): each XCD owns 4 bh -> K/V set 2MB < L2.
//  (c) T5: setprio(1) around the MFMA/exp2 cluster (2 independent blocks/CU).
//  (d) barrier before smem-reuse reduction (latent race fix).
__global__ __launch_bounds__(256, 2)
void attn_kernel(const unsigned short* __restrict__ Q,   // [32][2048][64] bf16
                 const unsigned short* __restrict__ K,   // [32][2048][64] bf16, pre-swizzled
                 const unsigned short* __restrict__ Vt,  // [32][64][2048] fp16, pre-swizzled
                 unsigned short* __restrict__ Aout) {    // [4096][1024] bf16
    __shared__ __align__(16) unsigned short smem[16384];  // sK[2][64*64] | sV[2][64*64]; reused as red
    __shared__ float lred[4][4][16];

    int tid = threadIdx.x, wave = tid >> 6, lane = tid & 63;
    int l15 = lane & 15, quad = lane >> 4;

    // XCD-chunked swizzle: id%8 = XCD (dispatch round-robin); give each XCD
    // a contiguous logical range -> 4 bh per XCD, K/V L2-resident.
    int id = blockIdx.x;                 // 0..1023
    int logical = (id & 7) * 128 + (id >> 3);
    int bh = logical >> 5, qt = logical & 31;
    int b = bh >> 4, h = bh & 15;
    int qr0 = qt * 64;

    const unsigned short* Qp = Q + (size_t)bh * SEQ * 64;
    const unsigned short* Kp = K + (size_t)bh * SEQ * 64;
    const unsigned short* Vp = Vt + (size_t)bh * 64 * SEQ;

    int srow = lane >> 3, scol = (lane & 7) * 8;   // 8 rows / 1KB per DMA call
    int wk0 = wave * 16;                           // this wave's key rows in tile

    // per-wave stage of one 64-key tile: 4 GLD16 (K: 2, V: 2), own rows only
#define STAGE(tile, pbase)                                                    \
    {                                                                         \
        _Pragma("unroll")                                                     \
        for (int j = 0; j < 2; j++) {                                         \
            int rb = wk0 + j * 8;                                             \
            GLD16(&Kp[(size_t)((tile) * 64 + rb + srow) * 64 + scol],         \
                  &smem[(pbase) + rb * 64]);                                  \
            GLD16(&Vp[(size_t)(rb + srow) * 2048 + (tile) * 64 + scol],       \
                  &smem[8192 + (pbase) + rb * 64]);                           \
        }                                                                     \
    }

    // Q fragments: B-operand col=q=l15, k=ks*32+quad*8 -> direct global loads, held in regs
    short8 qf[4][2];
#pragma unroll
    for (int nt = 0; nt < 4; nt++)
#pragma unroll
        for (int ks = 0; ks < 2; ks++)
            qf[nt][ks] = *(const short8*)&Qp[(size_t)(qr0 + nt * 16 + l15) * 64 + ks * 32 + quad * 8];

    STAGE(0, 0)
    STAGE(1, 4096)

    floatx4 of[4][4];   // O^T partial: [dt][nt], row=d=dt*16+quad*4+r, col=q=nt*16+l15
#pragma unroll
    for (int i = 0; i < 4; i++)
#pragma unroll
        for (int j = 0; j < 4; j++) of[i][j] = (floatx4){0.f, 0.f, 0.f, 0.f};
    float lsum[4] = {0.f, 0.f, 0.f, 0.f};

    int krow = wk0 + l15;
    int ksw = (l15 & 7) << 3;
    int kaddr0 = krow * 64 + ((quad * 8) ^ ksw);
    int kaddr1 = krow * 64 + ((32 + quad * 8) ^ ksw);
    int vcol = (wk0 + quad * 4) ^ ksw;             // vrow&7 == l15&7 for all dt

    asm volatile("s_waitcnt vmcnt(0)" ::: "memory");   // Q + tiles 0,1 staged
    __syncthreads();

    // compute one 64-key tile from buffer at ushort-offset pb (math identical to round-2)
    auto compute = [&](int pb) {
        __builtin_amdgcn_s_setprio(1);
        short8 kf0 = *(const short8*)&smem[pb + kaddr0];
        short8 kf1 = *(const short8*)&smem[pb + kaddr1];
        f16x4 pf[4];
#pragma unroll
        for (int nt = 0; nt < 4; nt++) {
            floatx4 zero = (floatx4){0.f, 0.f, 0.f, 0.f};
            floatx4 s = __builtin_amdgcn_mfma_f32_16x16x32_bf16(kf0, qf[nt][0], zero, 0, 0, 0);
            s = __builtin_amdgcn_mfma_f32_16x16x32_bf16(kf1, qf[nt][1], s, 0, 0, 0);
            float p0 = __builtin_amdgcn_exp2f(s[0]);
            float p1 = __builtin_amdgcn_exp2f(s[1]);
            float p2 = __builtin_amdgcn_exp2f(s[2]);
            float p3 = __builtin_amdgcn_exp2f(s[3]);
            lsum[nt] += (p0 + p1) + (p2 + p3);
            uint2v u;
            u.x = pk_f16(p0, p1);
            u.y = pk_f16(p2, p3);
            pf[nt] = __builtin_bit_cast(f16x4, u);
        }
#pragma unroll
        for (int dt = 0; dt < 4; dt++) {
            int vrow = dt * 16 + l15;
            ushort4v vv = *(const ushort4v*)&smem[8192 + pb + vrow * 64 + vcol];
            f16x4 vf = __builtin_bit_cast(f16x4, vv);
#pragma unroll
            for (int nt = 0; nt < 4; nt++)
                of[dt][nt] = __builtin_amdgcn_mfma_f32_16x16x16f16(vf, pf[nt], of[dt][nt], 0, 0, 0);
        }
        __builtin_amdgcn_s_setprio(0);
    };

    // steady state: never drain vmcnt to 0; stage(kt+1) always 1 iteration in flight
#pragma unroll 2
    for (int kt = 0; kt < 30; kt++) {
        int pb = (kt & 1) * 4096;
        compute(pb);
        __builtin_amdgcn_sched_barrier(0);
        asm volatile("s_barrier" ::: "memory");          // all reads of b_p done
        STAGE(kt + 2, pb)                                // restage b_p with tile kt+2
        asm volatile("s_waitcnt vmcnt(4)" ::: "memory"); // stage(kt+1) landed
        asm volatile("s_barrier" ::: "memory");          // cross-wave visibility
        __builtin_amdgcn_sched_barrier(0);
    }
    // tail: kt=30 (b0), kt=31 (b1); stage(31) still in flight at entry
    compute(0);
    asm volatile("s_waitcnt vmcnt(0)" ::: "memory");
    asm volatile("s_barrier" ::: "memory");
    compute(4096);
#undef STAGE

    // ---- epilogue: cross-quad l reduce, then cross-wave O/l reduction via LDS ----
#pragma unroll
    for (int nt = 0; nt < 4; nt++) {
        float l = lsum[nt];
        l += __shfl_xor(l, 16, 64);
        l += __shfl_xor(l, 32, 64);
        lsum[nt] = l;
    }
    if (quad == 0) {
#pragma unroll
        for (int nt = 0; nt < 4; nt++) lred[wave][nt][l15] = lsum[nt];
    }
    __syncthreads();   // all tile reads done before smem is reused as reduction scratch

    float* red = (float*)smem;   // 8192 floats; slot(c,w) = ((c*4+w)*1024), layout [nt][lane][4]

#define RED_WRITE(C, DTC)                                                          \
    _Pragma("unroll")                                                              \
    for (int nt = 0; nt < 4; nt++)                                                 \
        *(floatx4*)&red[((C) * 4 + wave) * 1024 + nt * 256 + lane * 4] = of[DTC][nt];

#define RED_STORE(DT, C, W0, W1, W2)                                               \
    {                                                                              \
        size_t obase = (size_t)(b * SEQ + qr0) * 1024 + h * 64 + (DT) * 16 + quad * 4; \
        _Pragma("unroll")                                                          \
        for (int nt = 0; nt < 4; nt++) {                                           \
            floatx4 a0 = *(const floatx4*)&red[((C) * 4 + (W0)) * 1024 + nt * 256 + lane * 4]; \
            floatx4 a1 = *(const floatx4*)&red[((C) * 4 + (W1)) * 1024 + nt * 256 + lane * 4]; \
            floatx4 a2 = *(const floatx4*)&red[((C) * 4 + (W2)) * 1024 + nt * 256 + lane * 4]; \
            floatx4 s = of[DT][nt] + a0 + a1 + a2;                                 \
            float lt = lred[0][nt][l15] + lred[1][nt][l15] + lred[2][nt][l15] + lred[3][nt][l15]; \
            float inv = 1.f / lt;                                                  \
            uint2v o;                                                              \
            o.x = pk_bf16(s[0] * inv, s[1] * inv);                                 \
            o.y = pk_bf16(s[2] * inv, s[3] * inv);                                 \
            *(uint2v*)&Aout[obase + (size_t)(nt * 16 + l15) * 1024] = o;           \
        }                                                                          \
    }

    // round 1: everyone ships of[0] -> slot(0,w), of[1] -> slot(1,w)
    RED_WRITE(0, 0)
    RED_WRITE(1, 1)
    __syncthreads();
    if (wave == 0)      RED_STORE(0, 0, 1, 2, 3)
    else if (wave == 1) RED_STORE(1, 1, 0, 2, 3)
    __syncthreads();
    // round 2: everyone ships of[2] -> slot(0,w), of[3] -> slot(1,w)
    RED_WRITE(0, 2)
    RED_WRITE(1, 3)
    __syncthreads();
    if (wave == 2)      RED_STORE(2, 0, 0, 1, 3)
    else if (wave == 3) RED_STORE(3, 1, 0, 1, 2)
#undef RED_WRITE
#undef RED_STORE
}

extern "C" void kernel_launch(void* const* d_in, const int* in_sizes, int n_in,
                              void* d_out, int out_size, void* d_ws, size_t ws_size,
                              hipStream_t stream) {
    const float* x_t  = (const float*)d_in[0];
    const float* x_s  = (const float*)d_in[1];
    const float* W_q  = (const float*)d_in[2];
    const float* W_kv = (const float*)d_in[3];
    const float* W_f  = (const float*)d_in[4];
    const float* b_f  = (const float*)d_in[5];
    float* out = (float*)d_out;

    char* ws = (char*)d_ws;
    const size_t MB = 1u << 20;
    unsigned short* xt_bf = (unsigned short*)(ws);            // 8 MB
    unsigned short* xs_bf = (unsigned short*)(ws + 8 * MB);   // 8 MB
    unsigned short* wq_t  = (unsigned short*)(ws + 16 * MB);  // 2 MB
    unsigned short* wkv_t = (unsigned short*)(ws + 18 * MB);  // 4 MB
    unsigned short* wf_t  = (unsigned short*)(ws + 22 * MB);  // 2 MB
    unsigned short* q_ws  = (unsigned short*)(ws + 24 * MB);  // 8 MB
    unsigned short* k_ws  = (unsigned short*)(ws + 32 * MB);  // 8 MB (pre-swizzled)
    unsigned short* vt_ws = (unsigned short*)(ws + 40 * MB);  // 8 MB (fp16, pre-swizzled)
    unsigned short* a_ws  = (unsigned short*)(ws + 48 * MB);  // 8 MB (total 56 MB)

    // SCALE * log2(e) folded into x_t so attention logits are in log2 domain
    cvt2_kernel<<<8192, 256, 0, stream>>>((const float4*)x_t, (const float4*)x_s,
                                          (ushort4*)xt_bf, (ushort4*)xs_bf,
                                          0.125f * 1.44269504088896340736f);
    transpose_all<<<4096, dim3(32, 8), 0, stream>>>(W_q, W_kv, W_f, wq_t, wkv_t, wf_t);

    gemm_qkv<<<dim3(24, 32), 256, 0, stream>>>(xt_bf, xs_bf, wq_t, wkv_t, q_ws, k_ws, vt_ws);
    attn_kernel<<<1024, 256, 0, stream>>>(q_ws, k_ws, vt_ws, a_ws);
    gemm_fuse<<<dim3(16, 32), 256, 0, stream>>>(a_ws, wf_t, out, b_f);
}

// Round 4
// 201.373 us; speedup vs baseline: 1.0649x; 1.0624x over previous
//
#include <hip/hip_runtime.h>

#define SEQ 2048

typedef short short8 __attribute__((ext_vector_type(8)));   // 8 bf16 (4 VGPRs)
typedef float floatx4 __attribute__((ext_vector_type(4)));  // 4 fp32 acc
typedef unsigned int uint2v __attribute__((ext_vector_type(2)));
typedef unsigned int uint4v __attribute__((ext_vector_type(4)));
typedef __fp16 f16x8 __attribute__((ext_vector_type(8)));   // 8 f16 (4 VGPRs) MFMA operand

static __device__ __forceinline__ unsigned short f2bf(float f) {
    unsigned int u = __builtin_bit_cast(unsigned int, f);
    u = (u + 0x7fffu + ((u >> 16) & 1u)) >> 16;   // RNE
    return (unsigned short)u;
}

// pack two fp32 -> two bf16 (RNE); HW instr if available (round-6 proven)
#if __has_builtin(__builtin_amdgcn_cvt_pk_bf16_f32)
typedef __bf16 bf16x2 __attribute__((ext_vector_type(2)));
static __device__ __forceinline__ unsigned int pk_bf16(float a, float b) {
    bf16x2 v = __builtin_amdgcn_cvt_pk_bf16_f32(a, b);
    return __builtin_bit_cast(unsigned int, v);
}
#else
static __device__ __forceinline__ unsigned int pk_bf16(float a, float b) {
    return (unsigned int)f2bf(a) | ((unsigned int)f2bf(b) << 16);
}
#endif

// pack two fp32 -> two fp16 (RTZ); return raw u32
static __device__ __forceinline__ unsigned int pk_f16(float a, float b) {
    auto v = __builtin_amdgcn_cvt_pkrtz(a, b);    // __fp16 x2
    return __builtin_bit_cast(unsigned int, v);
}

// async global->LDS, 16 B/lane; LDS dest = wave-uniform base + lane*16
#define GLD16(gp, lp)                                                        \
    __builtin_amdgcn_global_load_lds(                                        \
        (const __attribute__((address_space(1))) unsigned int*)(gp),         \
        (__attribute__((address_space(3))) unsigned int*)(lp), 16, 0, 0)

// ---------------- fused fp32 -> bf16 convert (x_t scaled, x_s plain) ----------------
__global__ void cvt2_kernel(const float4* __restrict__ a, const float4* __restrict__ b,
                            ushort4* __restrict__ oa, ushort4* __restrict__ ob, float sa) {
    int i = blockIdx.x * blockDim.x + threadIdx.x;
    if (i < 1048576) {
        float4 v = a[i];
        ushort4 o;
        o.x = f2bf(v.x * sa); o.y = f2bf(v.y * sa);
        o.z = f2bf(v.z * sa); o.w = f2bf(v.w * sa);
        oa[i] = o;
    } else {
        int j = i - 1048576;
        float4 v = b[j];
        ushort4 o;
        o.x = f2bf(v.x); o.y = f2bf(v.y);
        o.z = f2bf(v.z); o.w = f2bf(v.w);
        ob[j] = o;
    }
}

// ---------------- merged weight transposes: W [K][N] fp32 -> Wt [N][K] bf16 --------
__global__ void transpose_all(const float* __restrict__ Wq, const float* __restrict__ Wkv,
                              const float* __restrict__ Wf,
                              unsigned short* __restrict__ oq, unsigned short* __restrict__ okv,
                              unsigned short* __restrict__ of_) {
    __shared__ float tile[32][33];
    int bx = blockIdx.x;
    const float* in; unsigned short* out; int N, t;
    if (bx < 1024)      { in = Wq;  out = oq;  N = 1024; t = bx; }
    else if (bx < 3072) { in = Wkv; out = okv; N = 2048; t = bx - 1024; }
    else                { in = Wf;  out = of_; N = 1024; t = bx - 3072; }
    int nb = N >> 5;
    int n0 = (t % nb) * 32, k0 = (t / nb) * 32;   // K = 1024 always
    int tx = threadIdx.x, ty = threadIdx.y;
#pragma unroll
    for (int i = 0; i < 4; i++)
        tile[ty + i * 8][tx] = in[(size_t)(k0 + ty + i * 8) * N + n0 + tx];
    __syncthreads();
#pragma unroll
    for (int i = 0; i < 4; i++)
        out[(size_t)(n0 + ty + i * 8) * 1024 + k0 + tx] = f2bf(tile[tx][ty + i * 8]);
}

// ---------------- fused q+kv projection GEMM ----------------
// Epilogue: K written PRE-SWIZZLED bf16 (d ^ ((n&7)<<3)) and V^T written
// PRE-SWIZZLED fp16 so attn can global_load_lds with linear dest (m173 pattern).
__global__ __launch_bounds__(256, 3)
void gemm_qkv(const unsigned short* __restrict__ xt,
              const unsigned short* __restrict__ xs,
              const unsigned short* __restrict__ wq,
              const unsigned short* __restrict__ wkv,
              unsigned short* __restrict__ q_ws,
              unsigned short* __restrict__ k_ws,
              unsigned short* __restrict__ vt_ws) {
    __shared__ unsigned short sA[128][64];   // unpadded: required by global_load_lds
    __shared__ unsigned short sB[128][64];
    int tid = threadIdx.x, wave = tid >> 6, lane = tid & 63;
    int l15 = lane & 15, quad = lane >> 4;
    int cx = blockIdx.x;
    bool isq = cx < 8;
    const unsigned short* A  = isq ? xt : xs;
    const unsigned short* Bt = isq ? wq : wkv;
    int C0 = (isq ? cx : cx - 8) * 128;
    int R0 = blockIdx.y * 128;
    int wr = (wave >> 1) * 64, wc = (wave & 1) * 64;
    int srow = lane >> 3, scol = (lane & 7) * 8;   // staging: 8 rows / 1KB call

    floatx4 acc[4][4];
#pragma unroll
    for (int i = 0; i < 4; i++)
#pragma unroll
        for (int j = 0; j < 4; j++) acc[i][j] = (floatx4){0.f, 0.f, 0.f, 0.f};

    for (int kt = 0; kt < 16; kt++) {
        __syncthreads();                       // prev tile reads done
#pragma unroll
        for (int c = 0; c < 4; c++) {
            int rb = wave * 32 + c * 8;        // wave-uniform LDS dest row
            GLD16(&A [(size_t)(R0 + rb + srow) * 1024 + kt * 64 + scol], &sA[rb][0]);
            GLD16(&Bt[(size_t)(C0 + rb + srow) * 1024 + kt * 64 + scol], &sB[rb][0]);
        }
        __syncthreads();                       // vmcnt(0) drain + barrier
#pragma unroll
        for (int ks = 0; ks < 2; ks++) {
            short8 af[4], bf[4];
#pragma unroll
            for (int mt = 0; mt < 4; mt++)
                af[mt] = *(const short8*)&sA[wr + mt * 16 + l15][ks * 32 + quad * 8];
#pragma unroll
            for (int nt = 0; nt < 4; nt++)
                bf[nt] = *(const short8*)&sB[wc + nt * 16 + l15][ks * 32 + quad * 8];
#pragma unroll
            for (int mt = 0; mt < 4; mt++)
#pragma unroll
                for (int nt = 0; nt < 4; nt++)
                    acc[mt][nt] = __builtin_amdgcn_mfma_f32_16x16x32_bf16(af[mt], bf[nt], acc[mt][nt], 0, 0, 0);
        }
    }

    int b = R0 >> 11, nb0 = (R0 & 2047) + wr;  // 128-row tile stays within one batch
#pragma unroll
    for (int mt = 0; mt < 4; mt++) {
#pragma unroll
        for (int nt = 0; nt < 4; nt++) {
            int col = C0 + wc + nt * 16 + l15;     // C/D: col=lane&15
            if (isq) {
                int h = col >> 6, d = col & 63;
#pragma unroll
                for (int r = 0; r < 4; r++) {      // C/D: row=quad*4+reg
                    int n = nb0 + mt * 16 + quad * 4 + r;
                    q_ws[((size_t)((b * 16 + h) * 2048 + n)) * 64 + d] = f2bf(acc[mt][nt][r]);
                }
            } else if (col < 1024) {               // k half: bf16, pre-swizzled
                int h = col >> 6, d = col & 63;
#pragma unroll
                for (int r = 0; r < 4; r++) {
                    int n = nb0 + mt * 16 + quad * 4 + r;
                    k_ws[((size_t)((b * 16 + h) * 2048 + n)) * 64 + (d ^ ((n & 7) << 3))] = f2bf(acc[mt][nt][r]);
                }
            } else {                               // v half -> fp16 vt[bh][d][n'], pre-swizzled
                int cc = col - 1024, h = cc >> 6, d = cc & 63;
                int n0 = nb0 + mt * 16 + quad * 4;
                int coln = (n0 & ~63) | ((n0 & 63) ^ ((d & 7) << 3));  // swz keeps 4-groups intact
                uint2v pk;
                pk.x = pk_f16(acc[mt][nt][0], acc[mt][nt][1]);
                pk.y = pk_f16(acc[mt][nt][2], acc[mt][nt][3]);
                *(uint2v*)&vt_ws[((size_t)((b * 16 + h) * 64 + d)) * 2048 + coln] = pk;
            }
        }
    }
}

// ---------------- fuse GEMM (round-5 proven version) ----------------
__global__ __launch_bounds__(256, 3)
void gemm_fuse(const unsigned short* __restrict__ A,
               const unsigned short* __restrict__ Bt,
               float* __restrict__ out, const float* __restrict__ bias) {
    __shared__ unsigned short sA[128][64];
    __shared__ unsigned short sB[64][64];
    int tid = threadIdx.x, wave = tid >> 6, lane = tid & 63;
    int l15 = lane & 15, quad = lane >> 4;
    int R0 = blockIdx.y * 128, C0 = blockIdx.x * 64;
    int wr = (wave >> 1) * 64, wc = (wave & 1) * 32;
    int srow = lane >> 3, scol = (lane & 7) * 8;

    floatx4 acc[4][2];
#pragma unroll
    for (int i = 0; i < 4; i++)
#pragma unroll
        for (int j = 0; j < 2; j++) acc[i][j] = (floatx4){0.f, 0.f, 0.f, 0.f};

    for (int kt = 0; kt < 16; kt++) {
        __syncthreads();
#pragma unroll
        for (int c = 0; c < 4; c++) {
            int rb = wave * 32 + c * 8;
            GLD16(&A[(size_t)(R0 + rb + srow) * 1024 + kt * 64 + scol], &sA[rb][0]);
        }
#pragma unroll
        for (int c = 0; c < 2; c++) {
            int rb = wave * 16 + c * 8;
            GLD16(&Bt[(size_t)(C0 + rb + srow) * 1024 + kt * 64 + scol], &sB[rb][0]);
        }
        __syncthreads();
#pragma unroll
        for (int ks = 0; ks < 2; ks++) {
            short8 af[4], bf[2];
#pragma unroll
            for (int mt = 0; mt < 4; mt++)
                af[mt] = *(const short8*)&sA[wr + mt * 16 + l15][ks * 32 + quad * 8];
#pragma unroll
            for (int nt = 0; nt < 2; nt++)
                bf[nt] = *(const short8*)&sB[wc + nt * 16 + l15][ks * 32 + quad * 8];
#pragma unroll
            for (int mt = 0; mt < 4; mt++)
#pragma unroll
                for (int nt = 0; nt < 2; nt++)
                    acc[mt][nt] = __builtin_amdgcn_mfma_f32_16x16x32_bf16(af[mt], bf[nt], acc[mt][nt], 0, 0, 0);
        }
    }

#pragma unroll
    for (int mt = 0; mt < 4; mt++) {
#pragma unroll
        for (int r = 0; r < 4; r++) {
            int row = R0 + wr + mt * 16 + quad * 4 + r;
#pragma unroll
            for (int nt = 0; nt < 2; nt++) {
                int col = C0 + wc + nt * 16 + l15;
                out[(size_t)row * 1024 + col] = acc[mt][nt][r] + bias[col];
            }
        }
    }
}

// ---------------- flash attention: key-split waves, paired tiles, K=32 PV ----------------
// Round-4 change (the PV fix): legacy v_mfma_f32_16x16x16_f16 measured ~20 cyc/instr
// (MfmaUtil arithmetic, round 3) = 84% of MFMA time. Process key-tiles in PAIRS:
// tile A's P (keys quad*4+r) fills B-fragment k=quad*8+{0..3}, tile B's P fills
// k=quad*8+{4..7} -> one tuned v_mfma_f32_16x16x32_f16 per (dt,nt) per PAIR.
// PV: 32 slow MFMA/2kt -> 16 fast. l via ones-row K=32 MFMA (kills lsum VALU adds
// + end shuffles). 4-tile ring (64KB LDS), counted-vmcnt staging per pair,
// barriers halved. XCD swizzle + setprio kept. Producer layouts unchanged.
__global__ __launch_bounds__(256, 2)
void attn_kernel(const unsigned short* __restrict__ Q,   // [32][2048][64] bf16
                 const unsigned short* __restrict__ K,   // [32][2048][64] bf16, pre-swizzled
                 const unsigned short* __restrict__ Vt,  // [32][64][2048] fp16, pre-swizzled
                 unsigned short* __restrict__ Aout) {    // [4096][1024] bf16
    __shared__ __align__(16) unsigned short smem[32768]; // K[2 slots][2 tiles][64][64] | V same
    __shared__ float lred[4][4][16];

    int tid = threadIdx.x, wave = tid >> 6, lane = tid & 63;
    int l15 = lane & 15, quad = lane >> 4;

    // XCD-chunked swizzle: id%8 = XCD; each XCD owns 4 bh -> K/V L2-resident.
    int id = blockIdx.x;                 // 0..1023
    int logical = (id & 7) * 128 + (id >> 3);
    int bh = logical >> 5, qt = logical & 31;
    int b = bh >> 4, h = bh & 15;
    int qr0 = qt * 64;

    const unsigned short* Qp = Q + (size_t)bh * SEQ * 64;
    const unsigned short* Kp = K + (size_t)bh * SEQ * 64;
    const unsigned short* Vp = Vt + (size_t)bh * 64 * SEQ;

    int srow = lane >> 3, scol = (lane & 7) * 8;   // 8 rows / 1KB per DMA call
    int wk0 = wave * 16;                           // this wave's key rows in tile

    // stage one 64-key tile (K + V) at K-region ushort offset kb (V at +16384)
#define STAGE(tile, kb)                                                       \
    {                                                                         \
        _Pragma("unroll")                                                     \
        for (int j = 0; j < 2; j++) {                                         \
            int rb = wk0 + j * 8;                                             \
            GLD16(&Kp[(size_t)((tile) * 64 + rb + srow) * 64 + scol],         \
                  &smem[(kb) + rb * 64]);                                     \
            GLD16(&Vp[(size_t)(rb + srow) * 2048 + (tile) * 64 + scol],       \
                  &smem[16384 + (kb) + rb * 64]);                             \
        }                                                                     \
    }

    // Q fragments: B-operand col=q=l15, k=ks*32+quad*8 -> direct global loads, in regs
    short8 qf[4][2];
#pragma unroll
    for (int nt = 0; nt < 4; nt++)
#pragma unroll
        for (int ks = 0; ks < 2; ks++)
            qf[nt][ks] = *(const short8*)&Qp[(size_t)(qr0 + nt * 16 + l15) * 64 + ks * 32 + quad * 8];

    STAGE(0, 0) STAGE(1, 4096) STAGE(2, 8192) STAGE(3, 12288)

    floatx4 of[4][4];   // O^T partial: [dt][nt], row=d=dt*16+quad*4+r, col=q=nt*16+l15
#pragma unroll
    for (int i = 0; i < 4; i++)
#pragma unroll
        for (int j = 0; j < 4; j++) of[i][j] = (floatx4){0.f, 0.f, 0.f, 0.f};
    floatx4 of_l[4];    // l accumulator per nt (ones-row MFMA; all regs = l[q])
#pragma unroll
    for (int i = 0; i < 4; i++) of_l[i] = (floatx4){0.f, 0.f, 0.f, 0.f};

    f16x8 vones;
#pragma unroll
    for (int i = 0; i < 8; i++) vones[i] = (__fp16)1.0f;

    int krow = wk0 + l15;
    int ksw = (l15 & 7) << 3;
    int kaddr0 = krow * 64 + ((quad * 8) ^ ksw);
    int kaddr1 = krow * 64 + ((32 + quad * 8) ^ ksw);
    int vcol = (wk0 + quad * 4) ^ ksw;             // d&7 == l15&7 for all dt

    asm volatile("s_waitcnt vmcnt(0)" ::: "memory");   // Q + tiles 0..3 staged
    __syncthreads();

    // compute one PAIR of key-tiles: K slot base kb (tile A at kb, tile B at kb+4096)
    auto compute_pair = [&](int kb) {
        __builtin_amdgcn_s_setprio(1);
        uint2v pka[4], pkb[4];
        {   // tile A: S^T = K*Q^T, P = exp2(S) -> f16 pairs
            short8 kf0 = *(const short8*)&smem[kb + kaddr0];
            short8 kf1 = *(const short8*)&smem[kb + kaddr1];
#pragma unroll
            for (int nt = 0; nt < 4; nt++) {
                floatx4 z = (floatx4){0.f, 0.f, 0.f, 0.f};
                floatx4 s = __builtin_amdgcn_mfma_f32_16x16x32_bf16(kf0, qf[nt][0], z, 0, 0, 0);
                s = __builtin_amdgcn_mfma_f32_16x16x32_bf16(kf1, qf[nt][1], s, 0, 0, 0);
                pka[nt].x = pk_f16(__builtin_amdgcn_exp2f(s[0]), __builtin_amdgcn_exp2f(s[1]));
                pka[nt].y = pk_f16(__builtin_amdgcn_exp2f(s[2]), __builtin_amdgcn_exp2f(s[3]));
            }
        }
        {   // tile B
            short8 kf0 = *(const short8*)&smem[kb + 4096 + kaddr0];
            short8 kf1 = *(const short8*)&smem[kb + 4096 + kaddr1];
#pragma unroll
            for (int nt = 0; nt < 4; nt++) {
                floatx4 z = (floatx4){0.f, 0.f, 0.f, 0.f};
                floatx4 s = __builtin_amdgcn_mfma_f32_16x16x32_bf16(kf0, qf[nt][0], z, 0, 0, 0);
                s = __builtin_amdgcn_mfma_f32_16x16x32_bf16(kf1, qf[nt][1], s, 0, 0, 0);
                pkb[nt].x = pk_f16(__builtin_amdgcn_exp2f(s[0]), __builtin_amdgcn_exp2f(s[1]));
                pkb[nt].y = pk_f16(__builtin_amdgcn_exp2f(s[2]), __builtin_amdgcn_exp2f(s[3]));
            }
        }
        // PV with K=32: A = V^T frag (4 f16 from tile A buf + 4 from tile B buf),
        // B = P frag (pka | pkb). O^T[d][q] += sum over 32 keys.
#pragma unroll
        for (int dt = 0; dt < 4; dt++) {
            int vbase = 16384 + kb + (dt * 16 + l15) * 64 + vcol;
            uint2v va = *(const uint2v*)&smem[vbase];
            uint2v vb = *(const uint2v*)&smem[vbase + 4096];
            f16x8 vf = __builtin_bit_cast(f16x8, (uint4v){va.x, va.y, vb.x, vb.y});
#pragma unroll
            for (int nt = 0; nt < 4; nt++) {
                f16x8 pf = __builtin_bit_cast(f16x8, (uint4v){pka[nt].x, pka[nt].y, pkb[nt].x, pkb[nt].y});
                of[dt][nt] = __builtin_amdgcn_mfma_f32_16x16x32_f16(vf, pf, of[dt][nt], 0, 0, 0);
            }
        }
        // l[q] += sum_key P: ones-row MFMA (k-sum spans quads -> no shuffles)
#pragma unroll
        for (int nt = 0; nt < 4; nt++) {
            f16x8 pf = __builtin_bit_cast(f16x8, (uint4v){pka[nt].x, pka[nt].y, pkb[nt].x, pkb[nt].y});
            of_l[nt] = __builtin_amdgcn_mfma_f32_16x16x32_f16(vones, pf, of_l[nt], 0, 0, 0);
        }
        __builtin_amdgcn_s_setprio(0);
    };

    // steady state: 16 pairs; stage pair p+2 while computing pair p; vmcnt(8)
    // waits pair p+1 (never drains to 0 in the main loop)
#pragma unroll 2
    for (int p = 0; p < 14; p++) {
        int kb = (p & 1) * 8192;
        compute_pair(kb);
        __builtin_amdgcn_sched_barrier(0);
        asm volatile("s_barrier" ::: "memory");          // all reads of this slot done
        STAGE(2 * p + 4, kb)                             // restage slot with pair p+2
        STAGE(2 * p + 5, kb + 4096)
        asm volatile("s_waitcnt vmcnt(8)" ::: "memory"); // pair p+1 landed
        asm volatile("s_barrier" ::: "memory");          // cross-wave visibility
        __builtin_amdgcn_sched_barrier(0);
    }
    // tail: pair 14 (slot 0), pair 15 (slot 1); pair-15 DMAs still in flight at entry
    compute_pair(0);
    asm volatile("s_waitcnt vmcnt(0)" ::: "memory");
    asm volatile("s_barrier" ::: "memory");
    compute_pair(8192);
#undef STAGE

    // ---- epilogue: l is already k-reduced across quads; cross-wave via lred ----
    if (quad == 0) {
#pragma unroll
        for (int nt = 0; nt < 4; nt++) lred[wave][nt][l15] = of_l[nt][0];
    }
    __syncthreads();   // all tile reads done before smem is reused as reduction scratch

    float* red = (float*)smem;   // 8192 floats; slot(c,w) = ((c*4+w)*1024), layout [nt][lane][4]

#define RED_WRITE(C, DTC)                                                          \
    _Pragma("unroll")                                                              \
    for (int nt = 0; nt < 4; nt++)                                                 \
        *(floatx4*)&red[((C) * 4 + wave) * 1024 + nt * 256 + lane * 4] = of[DTC][nt];

#define RED_STORE(DT, C, W0, W1, W2)                                               \
    {                                                                              \
        size_t obase = (size_t)(b * SEQ + qr0) * 1024 + h * 64 + (DT) * 16 + quad * 4; \
        _Pragma("unroll")                                                          \
        for (int nt = 0; nt < 4; nt++) {                                           \
            floatx4 a0 = *(const floatx4*)&red[((C) * 4 + (W0)) * 1024 + nt * 256 + lane * 4]; \
            floatx4 a1 = *(const floatx4*)&red[((C) * 4 + (W1)) * 1024 + nt * 256 + lane * 4]; \
            floatx4 a2 = *(const floatx4*)&red[((C) * 4 + (W2)) * 1024 + nt * 256 + lane * 4]; \
            floatx4 s = of[DT][nt] + a0 + a1 + a2;                                 \
            float lt = lred[0][nt][l15] + lred[1][nt][l15] + lred[2][nt][l15] + lred[3][nt][l15]; \
            float inv = 1.f / lt;                                                  \
            uint2v o;                                                              \
            o.x = pk_bf16(s[0] * inv, s[1] * inv);                                 \
            o.y = pk_bf16(s[2] * inv, s[3] * inv);                                 \
            *(uint2v*)&Aout[obase + (size_t)(nt * 16 + l15) * 1024] = o;           \
        }                                                                          \
    }

    // round 1: everyone ships of[0] -> slot(0,w), of[1] -> slot(1,w)
    RED_WRITE(0, 0)
    RED_WRITE(1, 1)
    __syncthreads();
    if (wave == 0)      RED_STORE(0, 0, 1, 2, 3)
    else if (wave == 1) RED_STORE(1, 1, 0, 2, 3)
    __syncthreads();
    // round 2: everyone ships of[2] -> slot(0,w), of[3] -> slot(1,w)
    RED_WRITE(0, 2)
    RED_WRITE(1, 3)
    __syncthreads();
    if (wave == 2)      RED_STORE(2, 0, 0, 1, 3)
    else if (wave == 3) RED_STORE(3, 1, 0, 1, 2)
#undef RED_WRITE
#undef RED_STORE
}

extern "C" void kernel_launch(void* const* d_in, const int* in_sizes, int n_in,
                              void* d_out, int out_size, void* d_ws, size_t ws_size,
                              hipStream_t stream) {
    const float* x_t  = (const float*)d_in[0];
    const float* x_s  = (const float*)d_in[1];
    const float* W_q  = (const float*)d_in[2];
    const float* W_kv = (const float*)d_in[3];
    const float* W_f  = (const float*)d_in[4];
    const float* b_f  = (const float*)d_in[5];
    float* out = (float*)d_out;

    char* ws = (char*)d_ws;
    const size_t MB = 1u << 20;
    unsigned short* xt_bf = (unsigned short*)(ws);            // 8 MB
    unsigned short* xs_bf = (unsigned short*)(ws + 8 * MB);   // 8 MB
    unsigned short* wq_t  = (unsigned short*)(ws + 16 * MB);  // 2 MB
    unsigned short* wkv_t = (unsigned short*)(ws + 18 * MB);  // 4 MB
    unsigned short* wf_t  = (unsigned short*)(ws + 22 * MB);  // 2 MB
    unsigned short* q_ws  = (unsigned short*)(ws + 24 * MB);  // 8 MB
    unsigned short* k_ws  = (unsigned short*)(ws + 32 * MB);  // 8 MB (pre-swizzled)
    unsigned short* vt_ws = (unsigned short*)(ws + 40 * MB);  // 8 MB (fp16, pre-swizzled)
    unsigned short* a_ws  = (unsigned short*)(ws + 48 * MB);  // 8 MB (total 56 MB)

    // SCALE * log2(e) folded into x_t so attention logits are in log2 domain
    cvt2_kernel<<<8192, 256, 0, stream>>>((const float4*)x_t, (const float4*)x_s,
                                          (ushort4*)xt_bf, (ushort4*)xs_bf,
                                          0.125f * 1.44269504088896340736f);
    transpose_all<<<4096, dim3(32, 8), 0, stream>>>(W_q, W_kv, W_f, wq_t, wkv_t, wf_t);

    gemm_qkv<<<dim3(24, 32), 256, 0, stream>>>(xt_bf, xs_bf, wq_t, wkv_t, q_ws, k_ws, vt_ws);
    attn_kernel<<<1024, 256, 0, stream>>>(q_ws, k_ws, vt_ws, a_ws);
    gemm_fuse<<<dim3(16, 32), 256, 0, stream>>>(a_ws, wf_t, out, b_f);
}